// Round 1
// baseline (216.783 us; speedup 1.0000x reference)
//
#include <hip/hip_runtime.h>
#include <math.h>

// Problem constants: B=8, T=16, P=197, C=1024, R=8
#define BB 8
#define TT 16
#define PP 197
#define CC 1024
#define RR 8
#define NSEQ  (BB * PP)          // 1576 LSTM sequences
#define NROWS (BB * TT * PP)     // 25216 independent rows for down/up projections
#define TP    (TT * PP)          // 3152
#define LORA_SCALE 2.0f          // alpha/rank = 16/8

__device__ __forceinline__ float sigf(float x) {
    x = fminf(fmaxf(x, -30.f), 30.f);
    return 1.0f / (1.0f + __expf(-x));
}
__device__ __forceinline__ float tanh_fast(float x) {
    x = fminf(fmaxf(x, -15.f), 15.f);
    float e = __expf(-2.0f * x);
    return (1.0f - e) / (1.0f + e);
}
__device__ __forceinline__ float dot4(const float4 a, const float4 b) {
    return a.x * b.x + a.y * b.y + a.z * b.z + a.w * b.w;
}

// ---------------------------------------------------------------------------
// Kernel A: LoRA down.  grid = 1576 blocks x 512 thr (8 waves), 2 rows/wave.
// dw (32 KB) staged in LDS once per block; wave does coalesced float4 row
// loads, 8-rank dot, 6-level butterfly reduce, masked 32B store to red_ws.
// Memory-bound on the 103 MB hs read; 16 waves/CU resident (VGPR<=128).
// ---------------------------------------------------------------------------
__global__ __launch_bounds__(512, 4) void k_down(const float* __restrict__ hs,
                                                 const float* __restrict__ dw,
                                                 const float* __restrict__ fm,
                                                 float* __restrict__ red) {
    __shared__ float4 w_lds[2048];          // dw as float4: 8*1024/4
    const int tid = threadIdx.x;
#pragma unroll
    for (int j = tid; j < 2048; j += 512) w_lds[j] = ((const float4*)dw)[j];
    __syncthreads();

    const int lane = tid & 63;
    const int wv   = blockIdx.x * 8 + (tid >> 6);
    const int row0 = wv * 2;                 // 12608 waves * 2 = 25216 rows

    float4 xr[2][4];
#pragma unroll
    for (int i = 0; i < 2; ++i) {
        const float* bp = hs + (size_t)(row0 + i) * CC;
#pragma unroll
        for (int k = 0; k < 4; ++k)
            xr[i][k] = *(const float4*)(bp + k * 256 + lane * 4);
    }

    float acc[2][8];
#pragma unroll
    for (int i = 0; i < 2; ++i)
#pragma unroll
        for (int r = 0; r < 8; ++r) acc[i][r] = 0.f;

#pragma unroll
    for (int r = 0; r < 8; ++r)
#pragma unroll
        for (int k = 0; k < 4; ++k) {
            const float4 w = w_lds[r * 256 + k * 64 + lane];
            acc[0][r] += dot4(xr[0][k], w);
            acc[1][r] += dot4(xr[1][k], w);
        }

#pragma unroll
    for (int d = 32; d >= 1; d >>= 1)
#pragma unroll
        for (int i = 0; i < 2; ++i)
#pragma unroll
            for (int r = 0; r < 8; ++r)
                acc[i][r] += __shfl_xor(acc[i][r], d, 64);

    if (lane == 0) {
#pragma unroll
        for (int i = 0; i < 2; ++i) {
            const int row = row0 + i;
            const int b = row / TP;
            const int rem = row - b * TP;
            const int t = rem / PP;
            const int p = rem - t * PP;
            const float m = fm[b * TT + t];
            float* op = red + ((size_t)t * NSEQ + b * PP + p) * RR;
            *(float4*)op       = make_float4(acc[i][0] * m, acc[i][1] * m,
                                             acc[i][2] * m, acc[i][3] * m);
            *(float4*)(op + 4) = make_float4(acc[i][4] * m, acc[i][5] * m,
                                             acc[i][6] * m, acc[i][7] * m);
        }
    }
}

// ---------------------------------------------------------------------------
// Kernel B: rank-8 LSTM, 8 sequences per wave (octet = one sequence, lane&7 =
// rank slot -> no redundant octets).  x held lane-local (each lane loads its
// sequence's full 8-vector), h broadcast within the octet via width-8 shfl.
// x for t+1 double-buffered in registers to keep loads off the serial chain.
// grid = 197 blocks x 64 thr; ~3-6 us total, occupancy irrelevant.
// ---------------------------------------------------------------------------
__global__ __launch_bounds__(64, 1) void k_lstm(const float* __restrict__ red,
                                                const float* __restrict__ wihp,
                                                const float* __restrict__ whhp,
                                                const float* __restrict__ bihp,
                                                const float* __restrict__ bhhp,
                                                const float* __restrict__ fm,
                                                float* __restrict__ hout) {
    const int lane = threadIdx.x;
    const int sub  = lane >> 3;               // which of the 8 sequences
    const int r    = lane & 7;                // rank slot within the sequence
    const int seq  = blockIdx.x * 8 + sub;    // 197*8 = 1576 exactly
    const int b    = seq / PP;

    float wi[4][8], wh[4][8], bias[4];        // gate order i,f,g,o
#pragma unroll
    for (int g = 0; g < 4; ++g) {
        const float* wp = wihp + (g * 8 + r) * 8;
        float4 a = *(const float4*)wp, b4 = *(const float4*)(wp + 4);
        wi[g][0] = a.x;  wi[g][1] = a.y;  wi[g][2] = a.z;  wi[g][3] = a.w;
        wi[g][4] = b4.x; wi[g][5] = b4.y; wi[g][6] = b4.z; wi[g][7] = b4.w;
        const float* hp = whhp + (g * 8 + r) * 8;
        float4 c4 = *(const float4*)hp, d4 = *(const float4*)(hp + 4);
        wh[g][0] = c4.x; wh[g][1] = c4.y; wh[g][2] = c4.z; wh[g][3] = c4.w;
        wh[g][4] = d4.x; wh[g][5] = d4.y; wh[g][6] = d4.z; wh[g][7] = d4.w;
        bias[g] = bihp[g * 8 + r] + bhhp[g * 8 + r];
    }

    float msk[TT];
#pragma unroll
    for (int t = 0; t < TT; ++t) msk[t] = fm[b * TT + t];

    const float* xp = red + (size_t)seq * RR;       // t = 0
    float4 xa = *(const float4*)xp;
    float4 xb = *(const float4*)(xp + 4);

    float h = 0.f, c = 0.f;
#pragma unroll
    for (int t = 0; t < TT; ++t) {
        float4 na, nb;
        if (t < TT - 1) {                            // prefetch next step's x
            const float* np = red + ((size_t)(t + 1) * NSEQ + seq) * RR;
            na = *(const float4*)np;
            nb = *(const float4*)(np + 4);
        }
        const float xs[8] = {xa.x, xa.y, xa.z, xa.w, xb.x, xb.y, xb.z, xb.w};
        float gi = bias[0], gf = bias[1], gg = bias[2], go = bias[3];
#pragma unroll
        for (int j = 0; j < 8; ++j) {
            const float hv = __shfl(h, j, 8);        // octet-local broadcast
            gi += wi[0][j] * xs[j] + wh[0][j] * hv;
            gf += wi[1][j] * xs[j] + wh[1][j] * hv;
            gg += wi[2][j] * xs[j] + wh[2][j] * hv;
            go += wi[3][j] * xs[j] + wh[3][j] * hv;
        }
        c = sigf(gf) * c + sigf(gi) * tanh_fast(gg);
        h = sigf(go) * tanh_fast(c);
        // 64 lanes -> 256B contiguous store
        hout[((size_t)t * NSEQ + seq) * RR + r] = h * msk[t] * LORA_SCALE;
        if (t < TT - 1) { xa = na; xb = nb; }
    }
}

// ---------------------------------------------------------------------------
// Kernel C: LoRA up.  grid = 788 blocks x 512 thr (8 waves), 4 rows/wave.
// up transposed into LDS as upT[r][col] (conflict-free ds_read_b128; 2:1
// LDS:HBM byte ratio), h (already masked+scaled) broadcast-loaded, float4
// stores (1 KB/instr).  Memory-bound on the 103 MB output write.
// ---------------------------------------------------------------------------
__global__ __launch_bounds__(512, 4) void k_up(const float* __restrict__ hsq,
                                               const float* __restrict__ up,
                                               float* __restrict__ out) {
    __shared__ float upT[8][1024];               // 32 KB, transposed
    const int tid = threadIdx.x;
#pragma unroll
    for (int c0 = tid; c0 < CC; c0 += 512) {
        float4 a  = *(const float4*)(up + (size_t)c0 * RR);
        float4 b4 = *(const float4*)(up + (size_t)c0 * RR + 4);
        upT[0][c0] = a.x;  upT[1][c0] = a.y;  upT[2][c0] = a.z;  upT[3][c0] = a.w;
        upT[4][c0] = b4.x; upT[5][c0] = b4.y; upT[6][c0] = b4.z; upT[7][c0] = b4.w;
    }
    __syncthreads();

    const int lane = tid & 63;
    const int wv   = blockIdx.x * 8 + (tid >> 6);
    const int row0 = wv * 4;                      // 6304 waves * 4 = 25216 rows

    float hv[4][8];
#pragma unroll
    for (int i = 0; i < 4; ++i) {
        const int row = row0 + i;
        const int b = row / TP;
        const int rem = row - b * TP;
        const int t = rem / PP;
        const int p = rem - t * PP;
        const float* hp = hsq + ((size_t)t * NSEQ + b * PP + p) * RR;
        float4 a  = *(const float4*)hp;
        float4 b4 = *(const float4*)(hp + 4);
        hv[i][0] = a.x;  hv[i][1] = a.y;  hv[i][2] = a.z;  hv[i][3] = a.w;
        hv[i][4] = b4.x; hv[i][5] = b4.y; hv[i][6] = b4.z; hv[i][7] = b4.w;
    }

#pragma unroll
    for (int g4 = 0; g4 < 4; ++g4) {
        float4 w[8];
#pragma unroll
        for (int r = 0; r < 8; ++r)
            w[r] = *(const float4*)&upT[r][g4 * 256 + lane * 4];
#pragma unroll
        for (int i = 0; i < 4; ++i) {
            float4 o = make_float4(0.f, 0.f, 0.f, 0.f);
#pragma unroll
            for (int r = 0; r < 8; ++r) {
                o.x += hv[i][r] * w[r].x;
                o.y += hv[i][r] * w[r].y;
                o.z += hv[i][r] * w[r].z;
                o.w += hv[i][r] * w[r].w;
            }
            *(float4*)(out + (size_t)(row0 + i) * CC + g4 * 256 + lane * 4) = o;
        }
    }
}

extern "C" void kernel_launch(void* const* d_in, const int* in_sizes, int n_in,
                              void* d_out, int out_size, void* d_ws, size_t ws_size,
                              hipStream_t stream) {
    const float* hs  = (const float*)d_in[0];  // (B,T,P,C)
    const float* fm  = (const float*)d_in[2];  // (B,T)
    const float* dw  = (const float*)d_in[3];  // (R,C)
    const float* wih = (const float*)d_in[4];  // (4R,R)
    const float* whh = (const float*)d_in[5];  // (4R,R)
    const float* bih = (const float*)d_in[6];  // (4R,)
    const float* bhh = (const float*)d_in[7];  // (4R,)
    const float* up  = (const float*)d_in[8];  // (C,R)
    float* out = (float*)d_out;

    // Workspace: red_ws (t-major, masked) at +0; h_ws (masked+scaled) at +1MB.
    // Each is 16*1576*8*4 = 806,912 B; total 2 MB.
    float* red_ws = (float*)d_ws;
    float* h_ws   = red_ws + (1 << 18);

    k_down<<<NSEQ, 512, 0, stream>>>(hs, dw, fm, red_ws);                 // 1576 blocks
    k_lstm<<<NSEQ / 8, 64, 0, stream>>>(red_ws, wih, whh, bih, bhh, fm, h_ws); // 197 blocks
    k_up<<<NROWS / 32, 512, 0, stream>>>(h_ws, up, out);                  // 788 blocks
}